// Round 1
// baseline (698.927 us; speedup 1.0000x reference)
//
#include <hip/hip_runtime.h>

// Fused dequant-gather embedding:
//   out[t, d] = (float)qweight[x[t], d] * scales[x[t], d/128]
// T = 32*2048 = 65536 tokens, D = 1024, G = 8 groups of 128.
// Memory-bound: ~540 MB traffic -> ~86 us floor at 6.3 TB/s.

#define DIM      1024
#define NGROUPS  8
#define GSIZE    128            // DIM / NGROUPS
#define CHUNKS_PER_ROW (DIM / 4) // 256 float4 chunks per row

__global__ __launch_bounds__(256) void quant_embed_gather_kernel(
    const int*   __restrict__ x,       // [T] token row indices (int32)
    const int*   __restrict__ qw,      // [VOCAB, DIM] int4 codes stored as int32
    const float* __restrict__ sc,      // [VOCAB, NGROUPS]
    float*       __restrict__ out,     // [T, DIM]
    int total_chunks)                  // T * CHUNKS_PER_ROW
{
    const int stride = gridDim.x * blockDim.x;
    for (int c = blockIdx.x * blockDim.x + threadIdx.x; c < total_chunks; c += stride) {
        const int token  = c >> 8;          // c / CHUNKS_PER_ROW
        const int within = c & 255;         // chunk index within the row
        const int row    = x[token];        // wave-uniform broadcast load

        // group of this chunk: elements [within*4, within*4+3] all in one group
        const int g = within >> 5;          // (within*4) / 128
        const float s = sc[row * NGROUPS + g];

        const long long qoff = ((long long)row << 10) + (within << 2);
        const int4 q = *reinterpret_cast<const int4*>(qw + qoff);

        float4 o;
        o.x = (float)q.x * s;
        o.y = (float)q.y * s;
        o.z = (float)q.z * s;
        o.w = (float)q.w * s;

        *reinterpret_cast<float4*>(out + ((long long)c << 2)) = o;
    }
}

extern "C" void kernel_launch(void* const* d_in, const int* in_sizes, int n_in,
                              void* d_out, int out_size, void* d_ws, size_t ws_size,
                              hipStream_t stream) {
    const int*   x  = (const int*)d_in[0];     // [65536]
    const int*   qw = (const int*)d_in[1];     // [128000*1024]
    const float* sc = (const float*)d_in[2];   // [128000*8]
    float* out = (float*)d_out;                // [65536*1024]

    const int total_chunks = out_size / 4;     // 16,777,216
    const int block = 256;
    const int grid  = 2048;                    // 8192 waves = full occupancy, grid-stride

    quant_embed_gather_kernel<<<grid, block, 0, stream>>>(x, qw, sc, out, total_chunks);
}